// Round 15
// baseline (243.485 us; speedup 1.0000x reference)
//
#include <hip/hip_runtime.h>

#define TT  200
#define IN  5
#define NH  32
#define FC1 20
#define CH  64
#define RSG 12          // h20 row stride in dwords (10 f16-pairs + 2 pad)

// ws layout (dword units):
//  [0,4096):      whh f32, lane-packed: l*64 + m*16 + j
//                 lane l=(u,p): row (l&31)+32m, dim 16*(l>>5)+j
//  [4096,6656):   wih f32, lane-packed: l*40 + m*10 + jj
//                 lane l=(u,p): row (l&31)+32m, dim 10*(l>>5)+jj
//  [6656,6784):   bias f32[128] = b_ih + b_hh
//  [8192, ...):   h20 table: row r=b*TT+t, 12 dwords (10 f16 pairs + pad)
#define WS_WHH  0
#define WS_WIH  4096
#define WS_BIAS 6656
#define WS_H20  8192

typedef float    f2  __attribute__((ext_vector_type(2)));
typedef float    f4  __attribute__((ext_vector_type(4)));
typedef _Float16 h2t __attribute__((ext_vector_type(2)));

__device__ __forceinline__ float sigm(float a) {
    return __builtin_amdgcn_rcpf(1.f + __expf(-a));
}
__device__ __forceinline__ float tanh_f(float a) {
    return fmaf(2.f, __builtin_amdgcn_rcpf(1.f + __expf(-2.f * a)), -1.f);
}
__device__ __forceinline__ h2t bc_h2(unsigned int v) {
    return __builtin_bit_cast(h2t, v);
}
__device__ __forceinline__ unsigned int h2bits(float a, float b) {
    return __builtin_bit_cast(unsigned int, h2t{(_Float16)a, (_Float16)b});
}

#define EXTF(dst, src, i0, i1) dst = __builtin_shufflevector(src, src, i0, i1)

// ---- prep: pack whh/wih (f32 lane layouts) + bias into ws ----
__global__ __launch_bounds__(256) void prep_w(
    const float* __restrict__ w_ih, const float* __restrict__ w_hh,
    const float* __restrict__ b_ih, const float* __restrict__ b_hh,
    unsigned int* __restrict__ ws)
{
    const int tid = blockIdx.x * 256 + threadIdx.x;
    float* wsf = (float*)ws;
    if (tid < 4096) {
        const int l = tid >> 6, k = tid & 63;
        const int m = k >> 4, j = k & 15;
        const int row = (l & 31) + 32 * m;
        const int dim = 16 * (l >> 5) + j;
        wsf[WS_WHH + tid] = w_hh[row * NH + dim];
    } else if (tid < 6656) {
        const int t2 = tid - WS_WIH;
        const int l = t2 / 40, k = t2 % 40;
        const int m = k / 10, jj = k % 10;
        const int row = (l & 31) + 32 * m;
        const int dim = 10 * (l >> 5) + jj;
        wsf[WS_WIH + t2] = w_ih[row * FC1 + dim];
    } else if (tid < 6784) {
        const int r = tid - WS_BIAS;
        wsf[WS_BIAS + r] = b_ih[r] + b_hh[r];
    }
}

// ---- prep: h20[b,t] = relu(fc1(x[b,t])) as f16 pairs (r13/r14-proven) ----
__global__ __launch_bounds__(256) void prep_h20(
    const float* __restrict__ x, const float* __restrict__ fc1_w,
    const float* __restrict__ fc1_b, unsigned int* __restrict__ ws, int nrows)
{
    const int r = blockIdx.x * 256 + threadIdx.x;
    if (r >= nrows) return;
    const float* xr = x + (size_t)r * IN;
    float xv[IN];
    #pragma unroll
    for (int i = 0; i < IN; ++i) xv[i] = xr[i];
    unsigned int ow[10];
    #pragma unroll
    for (int j = 0; j < FC1; j += 2) {
        float a0 = fc1_b[j], a1 = fc1_b[j + 1];
        #pragma unroll
        for (int i = 0; i < IN; ++i) {
            a0 = fmaf(fc1_w[j * IN + i],       xv[i], a0);
            a1 = fmaf(fc1_w[(j + 1) * IN + i], xv[i], a1);
        }
        ow[j >> 1] = h2bits(fmaxf(a0, 0.f), fmaxf(a1, 0.f));
    }
    unsigned int* dst = ws + WS_H20 + (size_t)r * RSG;
    *(uint4*)(dst)     = uint4{ow[0], ow[1], ow[2], ow[3]};
    *(uint4*)(dst + 4) = uint4{ow[4], ow[5], ow[6], ow[7]};
    *(uint2*)(dst + 8) = uint2{ow[8], ow[9]};
}

// One step. P0..P4 = this half's 5 h20 f16-pairs (dims 10p..10p+9).
// W_ih part via v_fma_mix (f16 x f32 -> f32); W_hh part via v_pk_fma_f32.
// No fences: DS ops on sh_h may-alias -> program order; same-wave DS = FIFO.
#define STEP(P0, P1, P2, P3, P4)                                              \
  {                                                                           \
    const f4* hp_ = (const f4*)(sh_h + 16 * p);                               \
    f4 h0_ = hp_[0], h1_ = hp_[1], h2_ = hp_[2], h3_ = hp_[3];                \
    f2 hf_[8];                                                                \
    EXTF(hf_[0], h0_, 0, 1); EXTF(hf_[1], h0_, 2, 3);                         \
    EXTF(hf_[2], h1_, 0, 1); EXTF(hf_[3], h1_, 2, 3);                         \
    EXTF(hf_[4], h2_, 0, 1); EXTF(hf_[5], h2_, 2, 3);                         \
    EXTF(hf_[6], h3_, 0, 1); EXTF(hf_[7], h3_, 2, 3);                         \
    h2t q0_ = bc_h2(P0), q1_ = bc_h2(P1), q2_ = bc_h2(P2);                    \
    h2t q3_ = bc_h2(P3), q4_ = bc_h2(P4);                                     \
    float dA_[4];                                                             \
    _Pragma("unroll")                                                         \
    for (int m = 0; m < 4; ++m) {                                             \
      float a0_ = sd[m], a1_ = 0.f;                                           \
      a0_ = fmaf((float)q0_.x, wih[10*m+0], a0_);                             \
      a1_ = fmaf((float)q0_.y, wih[10*m+1], a1_);                             \
      a0_ = fmaf((float)q1_.x, wih[10*m+2], a0_);                             \
      a1_ = fmaf((float)q1_.y, wih[10*m+3], a1_);                             \
      a0_ = fmaf((float)q2_.x, wih[10*m+4], a0_);                             \
      a1_ = fmaf((float)q2_.y, wih[10*m+5], a1_);                             \
      a0_ = fmaf((float)q3_.x, wih[10*m+6], a0_);                             \
      a1_ = fmaf((float)q3_.y, wih[10*m+7], a1_);                             \
      a0_ = fmaf((float)q4_.x, wih[10*m+8], a0_);                             \
      a1_ = fmaf((float)q4_.y, wih[10*m+9], a1_);                             \
      f2 pe_ = f2{0.f, 0.f}, po_ = f2{0.f, 0.f};                              \
      pe_ = __builtin_elementwise_fma(wh2[8*m+0], hf_[0], pe_);               \
      po_ = __builtin_elementwise_fma(wh2[8*m+1], hf_[1], po_);               \
      pe_ = __builtin_elementwise_fma(wh2[8*m+2], hf_[2], pe_);               \
      po_ = __builtin_elementwise_fma(wh2[8*m+3], hf_[3], po_);               \
      pe_ = __builtin_elementwise_fma(wh2[8*m+4], hf_[4], pe_);               \
      po_ = __builtin_elementwise_fma(wh2[8*m+5], hf_[5], po_);               \
      pe_ = __builtin_elementwise_fma(wh2[8*m+6], hf_[6], pe_);               \
      po_ = __builtin_elementwise_fma(wh2[8*m+7], hf_[7], po_);               \
      f2 ps_ = pe_ + po_;                                                     \
      dA_[m] = (a0_ + a1_) + (ps_.x + ps_.y);                                 \
    }                                                                         \
    const float g0_ = dA_[0] + __shfl_xor(dA_[0], 32);                        \
    const float g1_ = dA_[1] + __shfl_xor(dA_[1], 32);                        \
    const float g2_ = dA_[2] + __shfl_xor(dA_[2], 32);                        \
    const float g3_ = dA_[3] + __shfl_xor(dA_[3], 32);                        \
    const float gi_ = sigm(g0_);                                              \
    const float gf_ = sigm(g1_);                                              \
    const float gg_ = tanh_f(g2_);                                            \
    const float go_ = sigm(g3_);                                              \
    c = fmaf(gf_, c, gi_ * gg_);                                              \
    const float hv_ = go_ * tanh_f(c);                                        \
    if (p == 0) sh_h[u] = hv_;                                                \
  }

// One wave per batch element. Lane l = (u = l&31, p = l>>5).
// K-split: lane owns gate rows {u+32m, m=0..3} x its half of [h20(20)|h(32)].
template <bool GH>
__global__ __attribute__((amdgpu_waves_per_eu(3))) __launch_bounds__(64)
void lstm_fused(
    const float* __restrict__ x,
    const float* __restrict__ fc1_w,
    const float* __restrict__ fc1_b,
    const unsigned int* __restrict__ ws,
    const float* __restrict__ fc2_w,
    const float* __restrict__ fc2_b,
    float* __restrict__ out)
{
    const int b = blockIdx.x;
    const int l = threadIdx.x;
    const int u = l & 31;
    const int p = l >> 5;

    __shared__ __align__(16) float sh_h[NH];   // f32 h state, 128 B

    // W_hh: 64 f32 per lane as 32 f2 (16 dwordx4 loads, contiguous)
    f2 wh2[32];
    {
        const f4* wp = (const f4*)((const float*)ws + WS_WHH + l * 64);
        #pragma unroll
        for (int g = 0; g < 16; ++g) {
            f4 v = wp[g];
            EXTF(wh2[2*g],   v, 0, 1);
            EXTF(wh2[2*g+1], v, 2, 3);
        }
    }
    // W_ih: 40 f32 per lane (10 dwordx4 loads)
    float wih[40];
    {
        const f4* wp = (const f4*)((const float*)ws + WS_WIH + l * 40);
        #pragma unroll
        for (int g = 0; g < 10; ++g) {
            f4 v = wp[g];
            wih[4*g+0] = v.x; wih[4*g+1] = v.y;
            wih[4*g+2] = v.z; wih[4*g+3] = v.w;
        }
    }
    const float* biasf = (const float*)ws + WS_BIAS;
    float sd[4];
    #pragma unroll
    for (int m = 0; m < 4; ++m) sd[m] = (p == 0) ? biasf[u + 32 * m] : 0.f;

    if (l < NH) sh_h[l] = 0.f;   // DS FIFO orders vs later reads
    float c = 0.f;

    if constexpr (GH) {
        const unsigned int* h20p = ws + WS_H20;
        const unsigned int* rbase = h20p + (size_t)b * TT * RSG + 5 * p;
        unsigned int a0, a1, a2, a3, a4;
#define LOADROW(V0, V1, V2, V3, V4, t)                                        \
        { const unsigned int* rp_ = rbase + (size_t)(t) * RSG;                \
          (V0) = rp_[0]; (V1) = rp_[1]; (V2) = rp_[2];                        \
          (V3) = rp_[3]; (V4) = rp_[4]; }
        LOADROW(a0, a1, a2, a3, a4, 0);
        for (int t = 0; t < TT; ++t) {
            unsigned int n0, n1, n2, n3, n4;
            const int tn = (t + 1 < TT) ? (t + 1) : t;
            LOADROW(n0, n1, n2, n3, n4, tn);      // prefetch next row
            STEP(a0, a1, a2, a3, a4);
            a0 = n0; a1 = n1; a2 = n2; a3 = n3; a4 = n4;
        }
#undef LOADROW
    } else {
        __shared__ __align__(16) unsigned int h20c[CH * RSG];   // 3 KB
        const float* xb = x + (size_t)b * (TT * IN);
        for (int tc = 0; tc < TT; tc += CH) {
            {   // refill: lane l computes h20 row for t = tc + l
                const int t = tc + l;
                if (t < TT) {
                    float xv[IN];
                    #pragma unroll
                    for (int i = 0; i < IN; ++i) xv[i] = xb[t * IN + i];
                    unsigned int ow[10];
                    #pragma unroll
                    for (int j = 0; j < FC1; j += 2) {
                        float b0 = fc1_b[j], b1 = fc1_b[j + 1];
                        #pragma unroll
                        for (int i = 0; i < IN; ++i) {
                            b0 = fmaf(fc1_w[j * IN + i],       xv[i], b0);
                            b1 = fmaf(fc1_w[(j + 1) * IN + i], xv[i], b1);
                        }
                        ow[j >> 1] = h2bits(fmaxf(b0, 0.f), fmaxf(b1, 0.f));
                    }
                    unsigned int* dst = h20c + l * RSG;
                    *(uint4*)(dst)     = uint4{ow[0], ow[1], ow[2], ow[3]};
                    *(uint4*)(dst + 4) = uint4{ow[4], ow[5], ow[6], ow[7]};
                    *(uint2*)(dst + 8) = uint2{ow[8], ow[9]};
                }
            }
            __syncthreads();
            const int te = (TT - tc < CH) ? (TT - tc) : CH;
            for (int k = 0; k < te; ++k) {
                const unsigned int* rp_ = h20c + k * RSG + 5 * p;
                unsigned int a0 = rp_[0], a1 = rp_[1], a2 = rp_[2];
                unsigned int a3 = rp_[3], a4 = rp_[4];
                STEP(a0, a1, a2, a3, a4);
            }
            __syncthreads();
        }
    }

    __syncthreads();   // order final h writes vs epilogue
    if (l < 2) {
        float acc = fc2_b[l];
        #pragma unroll
        for (int k = 0; k < NH; ++k)
            acc = fmaf(fc2_w[l * NH + k], sh_h[k], acc);
        out[(size_t)b * 2 + l] = acc;
    }
}

extern "C" void kernel_launch(void* const* d_in, const int* in_sizes, int n_in,
                              void* d_out, int out_size, void* d_ws, size_t ws_size,
                              hipStream_t stream) {
    const float* x     = (const float*)d_in[0];
    const float* fc1_w = (const float*)d_in[1];
    const float* fc1_b = (const float*)d_in[2];
    const float* w_ih  = (const float*)d_in[3];
    const float* w_hh  = (const float*)d_in[4];
    const float* b_ih  = (const float*)d_in[5];
    const float* b_hh  = (const float*)d_in[6];
    const float* fc2_w = (const float*)d_in[7];
    const float* fc2_b = (const float*)d_in[8];
    float* out = (float*)d_out;
    unsigned int* ws = (unsigned int*)d_ws;

    const int B = in_sizes[0] / (TT * IN);
    const int nrows = B * TT;
    const size_t need = ((size_t)WS_H20 + (size_t)nrows * RSG) * 4;

    prep_w<<<dim3(27), dim3(256), 0, stream>>>(w_ih, w_hh, b_ih, b_hh, ws);
    if (ws_size >= need) {
        prep_h20<<<dim3((nrows + 255) / 256), dim3(256), 0, stream>>>(
            x, fc1_w, fc1_b, ws, nrows);
        lstm_fused<true><<<dim3(B), dim3(64), 0, stream>>>(
            x, fc1_w, fc1_b, ws, fc2_w, fc2_b, out);
    } else {
        lstm_fused<false><<<dim3(B), dim3(64), 0, stream>>>(
            x, fc1_w, fc1_b, ws, fc2_w, fc2_b, out);
    }
}

// Round 16
// 197.661 us; speedup vs baseline: 1.2318x; 1.2318x over previous
//
#include <hip/hip_runtime.h>

#define TT  200
#define IN  5
#define NH  32
#define FC1 20
#define CH  64
#define RSG 12          // h20 row stride in dwords (10 f16-pairs + 2 pad)

// ws layout (dword units):
//  [0,3584):   row-major weights: row r (0..127) x 28 dwords; dword j = f16
//              pair of dims (2j,2j+1) of [w_ih(20) | w_hh(32)]; j>=26 pad.
//  [3584,3712): bias f32[128] = b_ih + b_hh
//  [4096,...): h20 table: row r=b*TT+t, 12 dwords (10 f16 pairs + pad)
#define WS_BIAS 3584
#define WS_H20  4096

typedef _Float16 h2t __attribute__((ext_vector_type(2)));

#if __has_builtin(__builtin_amdgcn_fdot2)
#define FDOT2(a, b, c) __builtin_amdgcn_fdot2((a), (b), (c), false)
#else
__device__ __forceinline__ float FDOT2(h2t a, h2t b, float c) {
    return fmaf((float)a.x, (float)b.x, fmaf((float)a.y, (float)b.y, c));
}
#endif

__device__ __forceinline__ float tanh_f(float a) {
    return fmaf(2.f, __builtin_amdgcn_rcpf(1.f + __expf(-2.f * a)), -1.f);
}
__device__ __forceinline__ h2t bc_h2(unsigned int v) {
    return __builtin_bit_cast(h2t, v);
}
__device__ __forceinline__ unsigned int h2bits(float a, float b) {
    return __builtin_bit_cast(unsigned int, h2t{(_Float16)a, (_Float16)b});
}

// ---- prep: row-major f16 weight pairs + bias ----
__global__ __launch_bounds__(256) void prep_w(
    const float* __restrict__ w_ih, const float* __restrict__ w_hh,
    const float* __restrict__ b_ih, const float* __restrict__ b_hh,
    unsigned int* __restrict__ ws)
{
    const int tid = blockIdx.x * 256 + threadIdx.x;
    if (tid < 128 * 28) {
        const int row = tid / 28, j = tid % 28;
        const int d0 = 2 * j;
        float a = 0.f, b = 0.f;
        if (d0 < FC1)     { a = w_ih[row * FC1 + d0];      b = w_ih[row * FC1 + d0 + 1]; }
        else if (d0 < 52) { a = w_hh[row * NH + d0 - FC1]; b = w_hh[row * NH + d0 - FC1 + 1]; }
        ws[tid] = h2bits(a, b);
    } else if (tid < 128 * 28 + 128) {
        const int r = tid - 128 * 28;
        ((float*)(ws + WS_BIAS))[r] = b_ih[r] + b_hh[r];
    }
}

// ---- prep: h20[b,t] = relu(fc1(x[b,t])) as f16 pairs (r13-15 proven) ----
__global__ __launch_bounds__(256) void prep_h20(
    const float* __restrict__ x, const float* __restrict__ fc1_w,
    const float* __restrict__ fc1_b, unsigned int* __restrict__ ws, int nrows)
{
    const int r = blockIdx.x * 256 + threadIdx.x;
    if (r >= nrows) return;
    const float* xr = x + (size_t)r * IN;
    float xv[IN];
    #pragma unroll
    for (int i = 0; i < IN; ++i) xv[i] = xr[i];
    unsigned int ow[10];
    #pragma unroll
    for (int j = 0; j < FC1; j += 2) {
        float a0 = fc1_b[j], a1 = fc1_b[j + 1];
        #pragma unroll
        for (int i = 0; i < IN; ++i) {
            a0 = fmaf(fc1_w[j * IN + i],       xv[i], a0);
            a1 = fmaf(fc1_w[(j + 1) * IN + i], xv[i], a1);
        }
        ow[j >> 1] = h2bits(fmaxf(a0, 0.f), fmaxf(a1, 0.f));
    }
    unsigned int* dst = ws + WS_H20 + (size_t)r * RSG;
    *(uint4*)(dst)     = uint4{ow[0], ow[1], ow[2], ow[3]};
    *(uint4*)(dst + 4) = uint4{ow[4], ow[5], ow[6], ow[7]};
    *(uint2*)(dst + 8) = uint2{ow[8], ow[9]};
}

// One step. Q0,Q1 (uint4) + Q2 (uint2) = this sample's h20 row (10 pairs).
// Each lane: ONE gate row, full K=52 (26 dot2). wave1 -> act1 LDS; wave0
// mirrors i/f via shfl_xor, reads g/o broadcast, updates c/h.
#define STEP(Q0, Q1, Q2)                                                      \
  {                                                                           \
    const uint4* hp_ = (const uint4*)sh_h;                                    \
    uint4 hA_ = hp_[0], hB_ = hp_[1], hC_ = hp_[2], hD_ = hp_[3];             \
    float a0_ = bias, a1_ = 0.f;                                              \
    a0_ = FDOT2(wp[0],  bc_h2((Q0).x), a0_);                                  \
    a1_ = FDOT2(wp[1],  bc_h2((Q0).y), a1_);                                  \
    a0_ = FDOT2(wp[2],  bc_h2((Q0).z), a0_);                                  \
    a1_ = FDOT2(wp[3],  bc_h2((Q0).w), a1_);                                  \
    a0_ = FDOT2(wp[4],  bc_h2((Q1).x), a0_);                                  \
    a1_ = FDOT2(wp[5],  bc_h2((Q1).y), a1_);                                  \
    a0_ = FDOT2(wp[6],  bc_h2((Q1).z), a0_);                                  \
    a1_ = FDOT2(wp[7],  bc_h2((Q1).w), a1_);                                  \
    a0_ = FDOT2(wp[8],  bc_h2((Q2).x), a0_);                                  \
    a1_ = FDOT2(wp[9],  bc_h2((Q2).y), a1_);                                  \
    a0_ = FDOT2(wp[10], bc_h2(hA_.x), a0_);                                   \
    a1_ = FDOT2(wp[11], bc_h2(hA_.y), a1_);                                   \
    a0_ = FDOT2(wp[12], bc_h2(hA_.z), a0_);                                   \
    a1_ = FDOT2(wp[13], bc_h2(hA_.w), a1_);                                   \
    a0_ = FDOT2(wp[14], bc_h2(hB_.x), a0_);                                   \
    a1_ = FDOT2(wp[15], bc_h2(hB_.y), a1_);                                   \
    a0_ = FDOT2(wp[16], bc_h2(hB_.z), a0_);                                   \
    a1_ = FDOT2(wp[17], bc_h2(hB_.w), a1_);                                   \
    a0_ = FDOT2(wp[18], bc_h2(hC_.x), a0_);                                   \
    a1_ = FDOT2(wp[19], bc_h2(hC_.y), a1_);                                   \
    a0_ = FDOT2(wp[20], bc_h2(hC_.z), a0_);                                   \
    a1_ = FDOT2(wp[21], bc_h2(hC_.w), a1_);                                   \
    a0_ = FDOT2(wp[22], bc_h2(hD_.x), a0_);                                   \
    a1_ = FDOT2(wp[23], bc_h2(hD_.y), a1_);                                   \
    a0_ = FDOT2(wp[24], bc_h2(hD_.z), a0_);                                   \
    a1_ = FDOT2(wp[25], bc_h2(hD_.w), a1_);                                   \
    const float a_ = a0_ + a1_;                                               \
    const float s_ = fmaf(An, __builtin_amdgcn_rcpf(1.f + __expf(Bn * a_)), Cn); \
    if (w) act1[l] = s_;                                                      \
    __syncthreads();                                                          \
    if (!w) {                                                                 \
      const float xs_ = __shfl_xor(s_, 32);                                   \
      const float iv_ = p ? xs_ : s_;                                         \
      const float fv_ = p ? s_ : xs_;                                         \
      const float gg_ = act1[u];                                              \
      const float ov_ = act1[32 + u];                                         \
      c = fmaf(fv_, c, iv_ * gg_);                                            \
      const float hv_ = ov_ * tanh_f(c);                                      \
      if (p == 0) sh_h[u] = (_Float16)hv_;                                    \
    }                                                                         \
    __syncthreads();                                                          \
  }

// Two waves per batch element (block = 128). wave w: lane l owns gate row
// r = 64w + l with FULL K=52 as 26 f16 pairs (fits in registers, no spill).
template <bool GH>
__global__ __launch_bounds__(128) void lstm_fused(
    const float* __restrict__ x,
    const float* __restrict__ fc1_w,
    const float* __restrict__ fc1_b,
    const unsigned int* __restrict__ ws,
    const float* __restrict__ fc2_w,
    const float* __restrict__ fc2_b,
    float* __restrict__ out)
{
    const int b   = blockIdx.x;
    const int tid = threadIdx.x;
    const int w   = tid >> 6;
    const int l   = tid & 63;
    const int u   = l & 31;
    const int p   = l >> 5;

    __shared__ __align__(16) float act1[64];      // wave1's g (0-31), o (32-63)
    __shared__ __align__(16) _Float16 sh_h[NH];   // 64 B

    const int row = 64 * w + l;
    h2t wp[26];
    {
        const uint4* wb = (const uint4*)(ws + row * 28);
        #pragma unroll
        for (int g = 0; g < 6; ++g) {
            uint4 v = wb[g];
            wp[4*g+0] = bc_h2(v.x); wp[4*g+1] = bc_h2(v.y);
            wp[4*g+2] = bc_h2(v.z); wp[4*g+3] = bc_h2(v.w);
        }
        uint4 v = wb[6];
        wp[24] = bc_h2(v.x); wp[25] = bc_h2(v.y);
    }
    const float bias = ((const float*)(ws + WS_BIAS))[row];
    const bool isTanh = (w == 1) && (l < 32);     // g rows
    const float An = isTanh ? 2.f : 1.f;
    const float Bn = -An;
    const float Cn = isTanh ? -1.f : 0.f;

    if (tid < 16) ((unsigned int*)sh_h)[tid] = 0u;
    float c = 0.f;
    __syncthreads();

    if constexpr (GH) {
        const unsigned int* rb = ws + WS_H20 + (size_t)b * TT * RSG;
        uint4 q0 = *(const uint4*)(rb);
        uint4 q1 = *(const uint4*)(rb + 4);
        uint2 q2 = *(const uint2*)(rb + 8);
        for (int t = 0; t < TT; ++t) {
            const unsigned int* np = rb + (size_t)((t + 1 < TT) ? t + 1 : t) * RSG;
            uint4 n0 = *(const uint4*)(np);
            uint4 n1 = *(const uint4*)(np + 4);
            uint2 n2 = *(const uint2*)(np + 8);
            STEP(q0, q1, q2);
            q0 = n0; q1 = n1; q2 = n2;
        }
    } else {
        __shared__ __align__(16) unsigned int h20c[CH * RSG];   // 3 KB
        const float* xb = x + (size_t)b * (TT * IN);
        for (int tc = 0; tc < TT; tc += CH) {
            if (tid < CH) {   // wave0 computes h20 rows tc..tc+63
                const int t = tc + tid;
                if (t < TT) {
                    float xv[IN];
                    #pragma unroll
                    for (int i = 0; i < IN; ++i) xv[i] = xb[t * IN + i];
                    unsigned int ow[10];
                    #pragma unroll
                    for (int j = 0; j < FC1; j += 2) {
                        float b0 = fc1_b[j], b1 = fc1_b[j + 1];
                        #pragma unroll
                        for (int i = 0; i < IN; ++i) {
                            b0 = fmaf(fc1_w[j * IN + i],       xv[i], b0);
                            b1 = fmaf(fc1_w[(j + 1) * IN + i], xv[i], b1);
                        }
                        ow[j >> 1] = h2bits(fmaxf(b0, 0.f), fmaxf(b1, 0.f));
                    }
                    unsigned int* dst = h20c + tid * RSG;
                    *(uint4*)(dst)     = uint4{ow[0], ow[1], ow[2], ow[3]};
                    *(uint4*)(dst + 4) = uint4{ow[4], ow[5], ow[6], ow[7]};
                    *(uint2*)(dst + 8) = uint2{ow[8], ow[9]};
                }
            }
            __syncthreads();
            const int te = (TT - tc < CH) ? (TT - tc) : CH;
            for (int k = 0; k < te; ++k) {
                const unsigned int* rp = h20c + k * RSG;
                uint4 q0 = *(const uint4*)(rp);
                uint4 q1 = *(const uint4*)(rp + 4);
                uint2 q2 = *(const uint2*)(rp + 8);
                STEP(q0, q1, q2);
            }
            __syncthreads();
        }
    }

    if (tid < 2) {
        float acc = fc2_b[tid];
        #pragma unroll
        for (int k = 0; k < NH; ++k)
            acc = fmaf(fc2_w[tid * NH + k], (float)sh_h[k], acc);
        out[(size_t)b * 2 + tid] = acc;
    }
}

extern "C" void kernel_launch(void* const* d_in, const int* in_sizes, int n_in,
                              void* d_out, int out_size, void* d_ws, size_t ws_size,
                              hipStream_t stream) {
    const float* x     = (const float*)d_in[0];
    const float* fc1_w = (const float*)d_in[1];
    const float* fc1_b = (const float*)d_in[2];
    const float* w_ih  = (const float*)d_in[3];
    const float* w_hh  = (const float*)d_in[4];
    const float* b_ih  = (const float*)d_in[5];
    const float* b_hh  = (const float*)d_in[6];
    const float* fc2_w = (const float*)d_in[7];
    const float* fc2_b = (const float*)d_in[8];
    float* out = (float*)d_out;
    unsigned int* ws = (unsigned int*)d_ws;

    const int B = in_sizes[0] / (TT * IN);
    const int nrows = B * TT;
    const size_t need = ((size_t)WS_H20 + (size_t)nrows * RSG) * 4;

    prep_w<<<dim3(15), dim3(256), 0, stream>>>(w_ih, w_hh, b_ih, b_hh, ws);
    if (ws_size >= need) {
        prep_h20<<<dim3((nrows + 255) / 256), dim3(256), 0, stream>>>(
            x, fc1_w, fc1_b, ws, nrows);
        lstm_fused<true><<<dim3(B), dim3(128), 0, stream>>>(
            x, fc1_w, fc1_b, ws, fc2_w, fc2_b, out);
    } else {
        lstm_fused<false><<<dim3(B), dim3(128), 0, stream>>>(
            x, fc1_w, fc1_b, ws, fc2_w, fc2_b, out);
    }
}

// Round 17
// 187.876 us; speedup vs baseline: 1.2960x; 1.0521x over previous
//
#include <hip/hip_runtime.h>

#define TT  200
#define IN  5
#define NH  32
#define FC1 20
#define RSG 12            // h20 table row stride in dwords (10 f16 pairs + pad)

// ws layout (dword units):
//  [0,4096):  W fragments: frag ft = kt*8+tg (16), lane l (64), 4 dwords.
//             Lane l of frag (kt,tg) holds W[gate = tg*16 + (l&15)]
//             [k = kt*32 + (l>>4)*8 + 0..7] as f16 pairs (even k in low half).
//             W col k: k<20 -> w_ih[:,k]; 24<=k<56 -> w_hh[:,k-24];
//             k==62 -> bias (b_ih+b_hh); else 0.  (bias via X dim62 = 1.0)
//  [4096,..): h20 table: row r = sample*TT + t, 12 dwords (10 f16 pairs).
#define WS_WB   0
#define WS_H20  4096

typedef _Float16 f16x8 __attribute__((ext_vector_type(8)));
typedef float    f32x4 __attribute__((ext_vector_type(4)));
typedef _Float16 h2t   __attribute__((ext_vector_type(2)));

__device__ __forceinline__ float sigm(float a) {
    return __builtin_amdgcn_rcpf(1.f + __expf(-a));
}
__device__ __forceinline__ float tanh_f(float a) {
    return fmaf(2.f, __builtin_amdgcn_rcpf(1.f + __expf(-2.f * a)), -1.f);
}
__device__ __forceinline__ unsigned int h2bits(float a, float b) {
    return __builtin_bit_cast(unsigned int, h2t{(_Float16)a, (_Float16)b});
}
// X tile: 16 rows x 128 B; XOR-swizzle 16B blocks to spread banks per row
__device__ __forceinline__ int SWZ(int s, int byte) {
    return s * 128 + (byte ^ ((s & 7) << 4));
}

// ---- prep: W fragments (f16 pairs, MFMA A-operand lane layout) ----
__global__ __launch_bounds__(256) void prep_w(
    const float* __restrict__ w_ih, const float* __restrict__ w_hh,
    const float* __restrict__ b_ih, const float* __restrict__ b_hh,
    unsigned int* __restrict__ ws)
{
    const int tid = blockIdx.x * 256 + threadIdx.x;
    if (tid >= 4096) return;
    const int j  = tid & 3;
    const int l  = (tid >> 2) & 63;
    const int ft = tid >> 8;                 // 0..15
    const int kt = ft >> 3, tg = ft & 7;
    const int gate = tg * 16 + (l & 15);
    const int k0 = kt * 32 + ((l >> 4) << 3) + 2 * j;
    auto wcol = [&](int k) -> float {
        if (k < FC1)            return w_ih[gate * FC1 + k];
        if (k >= 24 && k < 56)  return w_hh[gate * NH + (k - 24)];
        if (k == 62)            return b_ih[gate] + b_hh[gate];
        return 0.f;
    };
    ws[WS_WB + tid] = h2bits(wcol(k0), wcol(k0 + 1));
}

// ---- prep: h20[sample,t] = relu(fc1(x)) as f16 pairs (r13-proven) ----
__global__ __launch_bounds__(256) void prep_h20(
    const float* __restrict__ x, const float* __restrict__ fc1_w,
    const float* __restrict__ fc1_b, unsigned int* __restrict__ ws, int nrows)
{
    const int r = blockIdx.x * 256 + threadIdx.x;
    if (r >= nrows) return;
    const float* xr = x + (size_t)r * IN;
    float xv[IN];
    #pragma unroll
    for (int i = 0; i < IN; ++i) xv[i] = xr[i];
    unsigned int ow[10];
    #pragma unroll
    for (int j = 0; j < FC1; j += 2) {
        float a0 = fc1_b[j], a1 = fc1_b[j + 1];
        #pragma unroll
        for (int i = 0; i < IN; ++i) {
            a0 = fmaf(fc1_w[j * IN + i],       xv[i], a0);
            a1 = fmaf(fc1_w[(j + 1) * IN + i], xv[i], a1);
        }
        ow[j >> 1] = h2bits(fmaxf(a0, 0.f), fmaxf(a1, 0.f));
    }
    unsigned int* dst = ws + WS_H20 + (size_t)r * RSG;
    *(uint4*)(dst)     = uint4{ow[0], ow[1], ow[2], ow[3]};
    *(uint4*)(dst + 4) = uint4{ow[4], ow[5], ow[6], ow[7]};
    *(uint2*)(dst + 8) = uint2{ow[8], ow[9]};
}

// One wave = 16 samples. gates D[128 x 16] = W[128x64] x X[64x16] via
// 16 MFMA/step. D layout (verified): col = sample = l&15,
// row-in-tile = (l>>4)*4 + r -> gate = tg*16 + (l>>4)*4 + r. Tiles:
// 0,1 = i (dims dd, 16+dd); 2,3 = f; 4,5 = g(tanh); 6,7 = o, dd=(l>>4)*4+r.
// c/h update lane-local; h written as 2 ds_write_b64. No barriers.
__global__ __attribute__((amdgpu_waves_per_eu(1, 4))) __launch_bounds__(64)
void lstm_mfma(const unsigned int* __restrict__ ws,
               const float* __restrict__ fc2_w,
               const float* __restrict__ fc2_b,
               float* __restrict__ out, int Btot)
{
    const int b  = blockIdx.x;
    const int l  = threadIdx.x;
    const int bs = b * 16;

    __shared__ __align__(16) unsigned int X[512];   // 2 KB
    char* Xb = (char*)X;

    // W fragments -> registers (16 x 4 VGPR)
    f16x8 Wf[16];
    #pragma unroll
    for (int ft = 0; ft < 16; ++ft)
        Wf[ft] = __builtin_bit_cast(f16x8,
                    *(const uint4*)(ws + WS_WB + ft * 256 + l * 4));

    // init X: zeros everywhere, then dim62 = 1.0h per row
    ((uint4*)X)[l]      = uint4{0u, 0u, 0u, 0u};
    ((uint4*)X)[64 + l] = uint4{0u, 0u, 0u, 0u};
    if (l < 16)
        *(unsigned short*)(Xb + SWZ(l, 124)) = 0x3C00;   // f16(1.0)

    // h20 gather base for this lane's sample (lanes 0-15 active)
    int samp = bs + ((l < 16) ? l : 0);
    if (samp >= Btot) samp = Btot - 1;
    const unsigned int* hrow = ws + WS_H20 + (size_t)samp * TT * RSG;

    uint4 q0, q1; uint2 q2;
    if (l < 16) {
        // stage h20(t=0)
        uint4 a = *(const uint4*)(hrow);
        uint4 b4 = *(const uint4*)(hrow + 4);
        uint2 c2 = *(const uint2*)(hrow + 8);
        *(uint4*)(Xb + SWZ(l, 0))  = a;
        *(uint4*)(Xb + SWZ(l, 16)) = b4;
        *(uint2*)(Xb + SWZ(l, 32)) = c2;
        // preload q = h20(t=1)
        const unsigned int* rp = hrow + RSG;
        q0 = *(const uint4*)(rp);
        q1 = *(const uint4*)(rp + 4);
        q2 = *(const uint2*)(rp + 8);
    }

    // loop-invariant LDS offsets
    const int axf0 = SWZ(l & 15, (l >> 4) * 16);          // X k 0-31 (B-frag kt0)
    const int axf1 = SWZ(l & 15, 64 + (l >> 4) * 16);     // X k 32-63 (kt1)
    const int hw0  = SWZ(l & 15, 48 + ((l >> 4) << 3));        // h dims dd..dd+3
    const int hw1  = SWZ(l & 15, 48 + 32 + ((l >> 4) << 3));   // h dims 16+dd..

    float c0[4] = {0.f, 0.f, 0.f, 0.f};
    float c1[4] = {0.f, 0.f, 0.f, 0.f};
    const f32x4 zero = {0.f, 0.f, 0.f, 0.f};

    for (int t = 0; t < TT; ++t) {
        // B-fragments for this step (X complete for t)
        f16x8 Xf0 = *(const f16x8*)(Xb + axf0);
        f16x8 Xf1 = *(const f16x8*)(Xb + axf1);

        // write h20(t+1) over the h20 area (read above already issued;
        // same-wave DS is FIFO), then prefetch h20(t+2) from global
        if (l < 16) {
            *(uint4*)(Xb + SWZ(l, 0))  = q0;
            *(uint4*)(Xb + SWZ(l, 16)) = q1;
            *(uint2*)(Xb + SWZ(l, 32)) = q2;
            const unsigned int* rp =
                hrow + (size_t)((t + 2 < TT) ? t + 2 : TT - 1) * RSG;
            q0 = *(const uint4*)(rp);
            q1 = *(const uint4*)(rp + 4);
            q2 = *(const uint2*)(rp + 8);
        }

        // 16 MFMA: acc[tg] = W[kt0,tg]*Xf0 + W[kt1,tg]*Xf1
        f32x4 acc[8];
        #pragma unroll
        for (int g = 0; g < 8; ++g) {
            acc[g] = __builtin_amdgcn_mfma_f32_16x16x32_f16(Wf[g],     Xf0, zero,   0, 0, 0);
            acc[g] = __builtin_amdgcn_mfma_f32_16x16x32_f16(Wf[8 + g], Xf1, acc[g], 0, 0, 0);
        }

        // activations + state update (lane-local)
        float hv0[4], hv1[4];
        #pragma unroll
        for (int r = 0; r < 4; ++r) {
            const float iv0 = sigm(acc[0][r]);
            const float fv0 = sigm(acc[2][r]);
            const float gv0 = tanh_f(acc[4][r]);
            const float ov0 = sigm(acc[6][r]);
            c0[r] = fmaf(fv0, c0[r], iv0 * gv0);
            hv0[r] = ov0 * tanh_f(c0[r]);
            const float iv1 = sigm(acc[1][r]);
            const float fv1 = sigm(acc[3][r]);
            const float gv1 = tanh_f(acc[5][r]);
            const float ov1 = sigm(acc[7][r]);
            c1[r] = fmaf(fv1, c1[r], iv1 * gv1);
            hv1[r] = ov1 * tanh_f(c1[r]);
        }
        // h(t+1) -> X (4 consecutive dims per write)
        *(uint2*)(Xb + hw0) = uint2{h2bits(hv0[0], hv0[1]), h2bits(hv0[2], hv0[3])};
        *(uint2*)(Xb + hw1) = uint2{h2bits(hv1[0], hv1[1]), h2bits(hv1[2], hv1[3])};
    }

    // fc2 on final h (read back from X; DS FIFO orders vs last writes)
    if (l < 16 && bs + l < Btot) {
        f16x8 H[4];
        #pragma unroll
        for (int k = 0; k < 4; ++k)
            H[k] = *(const f16x8*)(Xb + SWZ(l, 48 + 16 * k));
        float o0 = fc2_b[0], o1 = fc2_b[1];
        #pragma unroll
        for (int k = 0; k < 4; ++k) {
            #pragma unroll
            for (int e = 0; e < 8; ++e) {
                const float hd = (float)H[k][e];
                o0 = fmaf(fc2_w[8 * k + e],      hd, o0);
                o1 = fmaf(fc2_w[NH + 8 * k + e], hd, o1);
            }
        }
        out[(size_t)(bs + l) * 2 + 0] = o0;
        out[(size_t)(bs + l) * 2 + 1] = o1;
    }
}

extern "C" void kernel_launch(void* const* d_in, const int* in_sizes, int n_in,
                              void* d_out, int out_size, void* d_ws, size_t ws_size,
                              hipStream_t stream) {
    const float* x     = (const float*)d_in[0];
    const float* fc1_w = (const float*)d_in[1];
    const float* fc1_b = (const float*)d_in[2];
    const float* w_ih  = (const float*)d_in[3];
    const float* w_hh  = (const float*)d_in[4];
    const float* b_ih  = (const float*)d_in[5];
    const float* b_hh  = (const float*)d_in[6];
    const float* fc2_w = (const float*)d_in[7];
    const float* fc2_b = (const float*)d_in[8];
    float* out = (float*)d_out;
    unsigned int* ws = (unsigned int*)d_ws;

    const int B = in_sizes[0] / (TT * IN);
    const int nrows = B * TT;
    const int nb = (B + 15) / 16;

    prep_w<<<dim3(16), dim3(256), 0, stream>>>(w_ih, w_hh, b_ih, b_hh, ws);
    prep_h20<<<dim3((nrows + 255) / 256), dim3(256), 0, stream>>>(
        x, fc1_w, fc1_b, ws, nrows);
    lstm_mfma<<<dim3(nb), dim3(64), 0, stream>>>(ws, fc2_w, fc2_b, out, B);
}